// Round 4
// baseline (644.113 us; speedup 1.0000x reference)
//
#include <hip/hip_runtime.h>
#include <math.h>

#define HH 28
#define VV 784
#define EE 1512
#define TT 25
#define M0C 0.05

// d_ws layout (bytes):
//   ORDER int32 [784*784] @ 0          (2458624)
//   D2S   f32   [784*784] @ 2458624    (2458624)
//   M     f32   [128*784] @ 4917248    (401408)
//   F     f32   [128*784] @ 5318656    (401408)

#define DECODE(idx, A, B)                                                  \
  {                                                                        \
    if ((idx) < 756) {                                                     \
      int i_ = (idx) / 27, j_ = (idx) - i_ * 27;                           \
      A = i_ * HH + j_; B = A + 1;                                         \
    } else {                                                               \
      int q_ = (idx) - 756;                                                \
      int i_ = q_ / HH, j_ = q_ - i_ * HH;                                 \
      A = i_ * HH + j_; B = A + HH;                                        \
    }                                                                      \
  }

__global__ __launch_bounds__(256) void k_sortrows(int* __restrict__ ORDER, float* __restrict__ D2S) {
  __shared__ unsigned long long keys[1024];
  const int v = blockIdx.x;
  const int i1 = v / HH, j1 = v % HH;
  const double step = 1.0 / 27.0;
  const double c0v = (i1 == 27) ? 0.0 : 1.0 - (double)i1 * step;
  const double c1v = (j1 == 27) ? 1.0 : (double)j1 * step;
  for (int u = threadIdx.x; u < 1024; u += 256) {
    unsigned long long key = ~0ULL;
    if (u < VV) {
      int i2 = u / HH, j2 = u % HH;
      double c0u = (i2 == 27) ? 0.0 : 1.0 - (double)i2 * step;
      double c1u = (j2 == 27) ? 1.0 : (double)j2 * step;
      double dx = c0v - c0u, dy = c1v - c1u;
      float d2 = (float)(dx * dx + dy * dy);
      key = ((unsigned long long)__float_as_uint(d2) << 32) | (unsigned)u;
    }
    keys[u] = key;
  }
  __syncthreads();
  for (unsigned k = 2; k <= 1024; k <<= 1) {
    for (unsigned j = k >> 1; j; j >>= 1) {
      for (unsigned i = threadIdx.x; i < 1024; i += 256) {
        unsigned l = i ^ j;
        if (l > i) {
          unsigned long long a = keys[i], c = keys[l];
          if ((a > c) == ((i & k) == 0)) { keys[i] = c; keys[l] = a; }
        }
      }
      __syncthreads();
    }
  }
  for (int u = threadIdx.x; u < VV; u += 256) {
    unsigned long long key = keys[u];
    ORDER[v * VV + u] = (int)(key & 0xffffffffu);
    D2S[v * VV + u] = __uint_as_float((unsigned)(key >> 32));
  }
}

__global__ __launch_bounds__(256) void k_norm(const float* __restrict__ x, float* __restrict__ M) {
  const int b = blockIdx.x;
  const int tid = threadIdx.x;
  double s = 0.0;
  for (int i = tid; i < VV; i += 256) s += (double)x[b * VV + i];
  for (int off = 32; off; off >>= 1) s += __shfl_xor(s, off, 64);
  __shared__ double sred[4];
  __shared__ double Ssh;
  if ((tid & 63) == 0) sred[tid >> 6] = s;
  __syncthreads();
  if (tid == 0) {
    double S = sred[0] + sred[1] + sred[2] + sred[3];
    Ssh = (S > 1e-12) ? S : 1e-12;
  }
  __syncthreads();
  double S = Ssh;
  for (int i = tid; i < VV; i += 256) M[b * VV + i] = (float)((double)x[b * VV + i] / S);
}

__global__ __launch_bounds__(256) void k_dtm(const float* __restrict__ M, const int* __restrict__ ORDER,
                                             const float* __restrict__ D2S, float* __restrict__ F) {
  const int wid = threadIdx.x >> 6;
  const int lane = threadIdx.x & 63;
  const int task = blockIdx.x * 4 + wid;
  if (task >= 128 * VV) return;
  const int b = task / VV, v = task % VV;
  const int* ord = ORDER + v * VV;
  const float* d2s = D2S + v * VV;
  const float* mb = M + b * VV;
  double P = 0.0, acc = 0.0;
  for (int base = 0; base < VV; base += 64) {
    int k = base + lane;
    double mass = 0.0, d2 = 0.0;
    if (k < VV) { mass = (double)mb[ord[k]]; d2 = (double)d2s[k]; }
    double s = mass;
    #pragma unroll
    for (int off = 1; off < 64; off <<= 1) {
      double t = __shfl_up(s, off, 64);
      if (lane >= off) s += t;
    }
    double prefix = P + (s - mass);
    double room = M0C - prefix;
    room = room > 0.0 ? room : 0.0;
    double take = mass < room ? mass : room;
    double contrib = take * d2;
    #pragma unroll
    for (int off = 32; off; off >>= 1) contrib += __shfl_xor(contrib, off, 64);
    acc += contrib;
    double tot = __shfl(s, 63, 64);
    P += tot;
    if (P >= M0C) break;
  }
  if (lane == 0) F[b * VV + v] = (float)sqrt(acc / M0C + 1e-12);
}

__global__ __launch_bounds__(256) void k_main(const float* __restrict__ F,
                                              const float* __restrict__ w_topo, const float* __restrict__ b_topo,
                                              const float* __restrict__ w_fc, const float* __restrict__ b_fc,
                                              float* __restrict__ out) {
  const int b = blockIdx.x;
  const int tid = threadIdx.x;
  __shared__ float fv[VV];
  __shared__ unsigned long long keys[2048];
  __shared__ unsigned long long rmb[VV + 48];   // packed (f_bits<<32)|root; [784..831] per-lane dummies
  __shared__ unsigned long long pairs[VV];      // (birth_bits<<32)|death_bits
  __shared__ float feat[2 * TT];
  __shared__ float hbuf[100];
  __shared__ int cntS;
  for (int i = tid; i < VV; i += 256) {
    float f = F[b * VV + i];
    fv[i] = f;
    rmb[i] = ((unsigned long long)__float_as_uint(f) << 32) | (unsigned)i;
  }
  for (int i = VV + tid; i < VV + 48; i += 256)
    rmb[i] = 0xFFFFFFFFFFFFFFFFULL;  // low32 >= 784: never matches a young root
  __syncthreads();
  // sort keys: (w_bits << 32) | edge_idx, ascending -> stable
  for (int e = tid; e < 2048; e += 256) {
    unsigned long long key = ~0ULL;
    if (e < EE) {
      int aa, bb;
      DECODE(e, aa, bb);
      float w = fmaxf(fv[aa], fv[bb]);
      key = ((unsigned long long)__float_as_uint(w) << 32) | (unsigned)e;
    }
    keys[e] = key;
  }
  __syncthreads();
  for (unsigned k = 2; k <= 2048; k <<= 1) {
    for (unsigned j = k >> 1; j; j >>= 1) {
      for (unsigned i = tid; i < 2048; i += 256) {
        unsigned l = i ^ j;
        if (l > i) {
          unsigned long long a = keys[i], c = keys[l];
          if ((a > c) == ((i & k) == 0)) { keys[i] = c; keys[l] = a; }
        }
      }
      __syncthreads();
    }
  }
  // repack sorted keys: (w_bits<<32)|(aa<<10)|bb  (sentinels -> aa=bb=0, harmless)
  for (int e = tid; e < 2048; e += 256) {
    unsigned long long key = keys[e];
    unsigned idx = (unsigned)key;
    unsigned long long nk;
    if (idx < EE) {
      int aa, bb;
      DECODE((int)idx, aa, bb);
      nk = (key & 0xFFFFFFFF00000000ULL) | (unsigned)((aa << 10) | bb);
    } else {
      nk = 0xFFFFFFFF00000000ULL;
    }
    keys[e] = nk;
  }
  __syncthreads();
  // ---- serial Kruskal elder-rule union-find, wave 0, depth-2 pipelined, sparse writes ----
  if (tid < 64) {
    const int lane = tid;
    const int v12 = (lane < 16) ? (768 + lane) : (VV + lane - 16);
    unsigned long long p[13];
    #pragma unroll
    for (int s = 0; s < 12; ++s) p[s] = rmb[lane + 64 * s];
    p[12] = rmb[v12];
    const bool isl0 = (lane == 0);
    // prologue
    unsigned long long K0 = keys[0], K1 = keys[1], K2 = keys[2], K3 = keys[3];
    unsigned lo0 = (unsigned)K0, lo1 = (unsigned)K1, lo2 = (unsigned)K2;
    int a0i = lo0 >> 10, b0i = lo0 & 1023;
    int a1i = lo1 >> 10, b1i = lo1 & 1023;
    int a2i = lo2 >> 10, b2i = lo2 & 1023;
    unsigned w0 = (unsigned)(K0 >> 32), w1 = (unsigned)(K1 >> 32), w2 = (unsigned)(K2 >> 32);
    unsigned long long pa0 = rmb[a0i], pb0 = rmb[b0i];
    unsigned long long pa1 = rmb[a1i], pb1 = rmb[b1i];
    unsigned soY = 0xffffffffu;
    unsigned long long soP = 0;
    int cnt = 0;
    for (int e = 0; e < EE; ++e) {
      // reads for edge e+2 (see state <= e-1; patched with subs e, e+1 before use)
      unsigned long long pa2 = rmb[a2i], pb2 = rmb[b2i];
      // key for edge e+4 (e+4 <= 1515 < 2048, sentinel region safe)
      unsigned long long K4 = keys[e + 4];
      // process edge e
      unsigned ra = (unsigned)pa0, rb = (unsigned)pb0;
      bool diff = (ra != rb);
      unsigned fa = (unsigned)(pa0 >> 32), fb = (unsigned)(pb0 >> 32);
      bool ya = (fa >= fb);  // young = a-side on ties (reference semantics)
      unsigned young = ya ? ra : rb;
      unsigned long long oldp = ya ? pb0 : pa0;
      unsigned birth = ya ? fa : fb;
      unsigned subY = diff ? young : 0xffffffffu;
      unsigned long long subP = oldp;
      if (__builtin_amdgcn_readfirstlane((int)diff)) {  // wave-uniform scalar branch
        if (isl0) pairs[cnt] = ((unsigned long long)birth << 32) | w0;  // 1-lane write
        cnt++;
        // sparse map update: only matching slots get a store (exec-masked)
        #pragma unroll
        for (int s = 0; s < 12; ++s) {
          if ((unsigned)p[s] == young) {
            p[s] = oldp;
            rmb[lane + 64 * s] = oldp;
          }
        }
        if ((unsigned)p[12] == young) {
          p[12] = oldp;
          rmb[v12] = oldp;
        }
      }
      // patch in-flight values for edge e+1 with subs (e-1) then (e)
      pa1 = (((unsigned)pa1 == soY) ? soP : pa1);
      pb1 = (((unsigned)pb1 == soY) ? soP : pb1);
      pa1 = (((unsigned)pa1 == subY) ? subP : pa1);
      pb1 = (((unsigned)pb1 == subY) ? subP : pb1);
      // rotate pipeline
      pa0 = pa1; pb0 = pb1; pa1 = pa2; pb1 = pb2;
      soY = subY; soP = subP;
      w0 = w1; w1 = w2; w2 = (unsigned)(K3 >> 32);
      unsigned lo3 = (unsigned)K3;
      a2i = lo3 >> 10; b2i = lo3 & 1023;
      K3 = K4;
    }
    if (isl0) cntS = cnt;
  }
  __syncthreads();
  const int cnt = cntS;
  const int wid = tid >> 6, lane = tid & 63;
  // landscape: top-2 tents per t (zeros exist in ref's 1512-vector, so init 0 is exact)
  for (int t = wid; t < TT; t += 4) {
    double tvd = (t == 24) ? 0.5 : (double)t * (0.5 / 24.0);
    float tv = (float)tvd;
    float m1 = 0.0f, m2 = 0.0f;
    for (int pidx = lane; pidx < cnt; pidx += 64) {
      unsigned long long pr = pairs[pidx];
      float pbv = __uint_as_float((unsigned)(pr >> 32));
      float pdv = __uint_as_float((unsigned)pr);
      float tent = fminf(tv - pbv, pdv - tv);
      tent = fmaxf(tent, 0.0f);
      if (tent > m1) { m2 = m1; m1 = tent; }
      else if (tent > m2) { m2 = tent; }
    }
    #pragma unroll
    for (int off = 32; off; off >>= 1) {
      float o1 = __shfl_xor(m1, off, 64);
      float o2 = __shfl_xor(m2, off, 64);
      float n1 = fmaxf(m1, o1);
      float n2 = fmaxf(fminf(m1, o1), fmaxf(m2, o2));
      m1 = n1; m2 = n2;
    }
    if (lane == 0) { feat[t] = m1; feat[TT + t] = m2; }
  }
  __syncthreads();
  // MLP: relu(feat @ w_topo + b_topo) @ w_fc + b_fc
  if (tid < 100) {
    double h = (double)b_topo[tid];
    for (int k2 = 0; k2 < 50; ++k2) h += (double)feat[k2] * (double)w_topo[k2 * 100 + tid];
    hbuf[tid] = (h > 0.0) ? (float)h : 0.0f;
  }
  __syncthreads();
  if (tid < 10) {
    double o = (double)b_fc[tid];
    for (int k2 = 0; k2 < 100; ++k2) o += (double)hbuf[k2] * (double)w_fc[k2 * 10 + tid];
    out[b * 10 + tid] = (float)o;
  }
}

extern "C" void kernel_launch(void* const* d_in, const int* in_sizes, int n_in,
                              void* d_out, int out_size, void* d_ws, size_t ws_size,
                              hipStream_t stream) {
  const float* x = (const float*)d_in[0];
  const float* w_topo = (const float*)d_in[1];
  const float* b_topo = (const float*)d_in[2];
  const float* w_fc = (const float*)d_in[3];
  const float* b_fc = (const float*)d_in[4];
  float* outp = (float*)d_out;
  char* ws = (char*)d_ws;
  int* ORDER = (int*)ws;
  float* D2S = (float*)(ws + 2458624);
  float* M = (float*)(ws + 4917248);
  float* F = (float*)(ws + 5318656);

  hipLaunchKernelGGL(k_sortrows, dim3(VV), dim3(256), 0, stream, ORDER, D2S);
  hipLaunchKernelGGL(k_norm, dim3(128), dim3(256), 0, stream, x, M);
  hipLaunchKernelGGL(k_dtm, dim3((128 * VV + 3) / 4), dim3(256), 0, stream, M, ORDER, D2S, F);
  hipLaunchKernelGGL(k_main, dim3(128), dim3(256), 0, stream, F, w_topo, b_topo, w_fc, b_fc, outp);
}

// Round 5
// 246.995 us; speedup vs baseline: 2.6078x; 2.6078x over previous
//
#include <hip/hip_runtime.h>
#include <math.h>

#define HH 28
#define VV 784
#define EE 1512
#define TT 25
#define M0C 0.05

// d_ws layout (bytes):
//   ORDER int32 [784*784] @ 0          (2458624)
//   D2S   f32   [784*784] @ 2458624    (2458624)
//   M     f32   [128*784] @ 4917248    (401408)
//   F     f32   [128*784] @ 5318656    (401408)

#define DECODE(idx, A, B)                                                  \
  {                                                                        \
    if ((idx) < 756) {                                                     \
      int i_ = (idx) / 27, j_ = (idx) - i_ * 27;                           \
      A = i_ * HH + j_; B = A + 1;                                         \
    } else {                                                               \
      int q_ = (idx) - 756;                                                \
      int i_ = q_ / HH, j_ = q_ - i_ * HH;                                 \
      A = i_ * HH + j_; B = A + HH;                                        \
    }                                                                      \
  }

__global__ __launch_bounds__(256) void k_sortrows(int* __restrict__ ORDER, float* __restrict__ D2S) {
  __shared__ unsigned long long keys[1024];
  const int v = blockIdx.x;
  const int i1 = v / HH, j1 = v % HH;
  const double step = 1.0 / 27.0;
  const double c0v = (i1 == 27) ? 0.0 : 1.0 - (double)i1 * step;
  const double c1v = (j1 == 27) ? 1.0 : (double)j1 * step;
  for (int u = threadIdx.x; u < 1024; u += 256) {
    unsigned long long key = ~0ULL;
    if (u < VV) {
      int i2 = u / HH, j2 = u % HH;
      double c0u = (i2 == 27) ? 0.0 : 1.0 - (double)i2 * step;
      double c1u = (j2 == 27) ? 1.0 : (double)j2 * step;
      double dx = c0v - c0u, dy = c1v - c1u;
      float d2 = (float)(dx * dx + dy * dy);
      key = ((unsigned long long)__float_as_uint(d2) << 32) | (unsigned)u;
    }
    keys[u] = key;
  }
  __syncthreads();
  for (unsigned k = 2; k <= 1024; k <<= 1) {
    for (unsigned j = k >> 1; j; j >>= 1) {
      for (unsigned i = threadIdx.x; i < 1024; i += 256) {
        unsigned l = i ^ j;
        if (l > i) {
          unsigned long long a = keys[i], c = keys[l];
          if ((a > c) == ((i & k) == 0)) { keys[i] = c; keys[l] = a; }
        }
      }
      __syncthreads();
    }
  }
  for (int u = threadIdx.x; u < VV; u += 256) {
    unsigned long long key = keys[u];
    ORDER[v * VV + u] = (int)(key & 0xffffffffu);
    D2S[v * VV + u] = __uint_as_float((unsigned)(key >> 32));
  }
}

__global__ __launch_bounds__(256) void k_norm(const float* __restrict__ x, float* __restrict__ M) {
  const int b = blockIdx.x;
  const int tid = threadIdx.x;
  double s = 0.0;
  for (int i = tid; i < VV; i += 256) s += (double)x[b * VV + i];
  for (int off = 32; off; off >>= 1) s += __shfl_xor(s, off, 64);
  __shared__ double sred[4];
  __shared__ double Ssh;
  if ((tid & 63) == 0) sred[tid >> 6] = s;
  __syncthreads();
  if (tid == 0) {
    double S = sred[0] + sred[1] + sred[2] + sred[3];
    Ssh = (S > 1e-12) ? S : 1e-12;
  }
  __syncthreads();
  double S = Ssh;
  for (int i = tid; i < VV; i += 256) M[b * VV + i] = (float)((double)x[b * VV + i] / S);
}

__global__ __launch_bounds__(256) void k_dtm(const float* __restrict__ M, const int* __restrict__ ORDER,
                                             const float* __restrict__ D2S, float* __restrict__ F) {
  const int wid = threadIdx.x >> 6;
  const int lane = threadIdx.x & 63;
  const int task = blockIdx.x * 4 + wid;
  if (task >= 128 * VV) return;
  const int b = task / VV, v = task % VV;
  const int* ord = ORDER + v * VV;
  const float* d2s = D2S + v * VV;
  const float* mb = M + b * VV;
  double P = 0.0, acc = 0.0;
  for (int base = 0; base < VV; base += 64) {
    int k = base + lane;
    double mass = 0.0, d2 = 0.0;
    if (k < VV) { mass = (double)mb[ord[k]]; d2 = (double)d2s[k]; }
    double s = mass;
    #pragma unroll
    for (int off = 1; off < 64; off <<= 1) {
      double t = __shfl_up(s, off, 64);
      if (lane >= off) s += t;
    }
    double prefix = P + (s - mass);
    double room = M0C - prefix;
    room = room > 0.0 ? room : 0.0;
    double take = mass < room ? mass : room;
    double contrib = take * d2;
    #pragma unroll
    for (int off = 32; off; off >>= 1) contrib += __shfl_xor(contrib, off, 64);
    acc += contrib;
    double tot = __shfl(s, 63, 64);
    P += tot;
    if (P >= M0C) break;
  }
  if (lane == 0) F[b * VV + v] = (float)sqrt(acc / M0C + 1e-12);
}

__global__ __launch_bounds__(256) void k_main(const float* __restrict__ F,
                                              const float* __restrict__ w_topo, const float* __restrict__ b_topo,
                                              const float* __restrict__ w_fc, const float* __restrict__ b_fc,
                                              float* __restrict__ out) {
  const int b = blockIdx.x;
  const int tid = threadIdx.x;
  __shared__ float fv[VV];
  __shared__ unsigned long long keys[2048];
  __shared__ int par[VV];                   // union-find parent pointers
  __shared__ unsigned long long pairs[VV];  // (birth_bits<<32)|death_bits
  __shared__ float feat[2 * TT];
  __shared__ float hbuf[100];
  __shared__ int cntS;
  for (int i = tid; i < VV; i += 256) {
    fv[i] = F[b * VV + i];
    par[i] = i;
  }
  __syncthreads();
  // sort keys: (w_bits << 32) | edge_idx, ascending -> stable (matches jnp.argsort)
  for (int e = tid; e < 2048; e += 256) {
    unsigned long long key = ~0ULL;
    if (e < EE) {
      int aa, bb;
      DECODE(e, aa, bb);
      float w = fmaxf(fv[aa], fv[bb]);
      key = ((unsigned long long)__float_as_uint(w) << 32) | (unsigned)e;
    }
    keys[e] = key;
  }
  __syncthreads();
  for (unsigned k = 2; k <= 2048; k <<= 1) {
    for (unsigned j = k >> 1; j; j >>= 1) {
      for (unsigned i = tid; i < 2048; i += 256) {
        unsigned l = i ^ j;
        if (l > i) {
          unsigned long long a = keys[i], c = keys[l];
          if ((a > c) == ((i & k) == 0)) { keys[i] = c; keys[l] = a; }
        }
      }
      __syncthreads();
    }
  }
  // repack sorted keys: (w_bits<<32)|(aa<<10)|bb  (sentinels -> aa=bb=0: self-edge, never merges)
  for (int e = tid; e < 2048; e += 256) {
    unsigned long long key = keys[e];
    unsigned idx = (unsigned)key;
    unsigned long long nk;
    if (idx < EE) {
      int aa, bb;
      DECODE((int)idx, aa, bb);
      nk = (key & 0xFFFFFFFF00000000ULL) | (unsigned)((aa << 10) | bb);
    } else {
      nk = 0xFFFFFFFF00000000ULL;
    }
    keys[e] = nk;
  }
  __syncthreads();
  // ---- batched wave-parallel Kruskal elder-rule union-find (wave 0) ----
  // 64 edges per batch: parallel find (LDS parent chase), then a 64-step
  // in-register readlane sweep applies merges in exact sorted order.
  if (tid < 64) {
    const int lane = tid;
    int cntbase = 0;
    for (int batch = 0; batch < 24; ++batch) {
      unsigned long long K = keys[batch * 64 + lane];
      unsigned lo = (unsigned)K;
      int aa = (int)(lo >> 10), bb = (int)(lo & 1023);
      unsigned wbits = (unsigned)(K >> 32);
      // parallel find (state as of batch start)
      int ra = aa, rb = bb;
      for (;;) {
        int na = par[ra];
        int nb = par[rb];
        bool done = (na == ra) && (nb == rb);
        ra = na; rb = nb;
        if (__all(done)) break;
      }
      // path compression for queried vertices (same-root duplicates write same value)
      par[aa] = ra;
      par[bb] = rb;
      unsigned fa = __float_as_uint(fv[ra]);
      unsigned fb = __float_as_uint(fv[rb]);
      // serial in-register sweep: apply edges j=0..63 in order
      int sdiff = 0, syoung = 0, sold = 0;
      unsigned sbirth = 0;
      #pragma unroll 4
      for (int j = 0; j < 64; ++j) {
        int s_ra = __builtin_amdgcn_readlane(ra, j);
        int s_rb = __builtin_amdgcn_readlane(rb, j);
        if (s_ra != s_rb) {  // uniform (scalar) branch
          unsigned s_fa = (unsigned)__builtin_amdgcn_readlane((int)fa, j);
          unsigned s_fb = (unsigned)__builtin_amdgcn_readlane((int)fb, j);
          bool ya = (s_fa >= s_fb);  // young = a-side on ties (reference semantics)
          int young = ya ? s_ra : s_rb;
          int oldv = ya ? s_rb : s_ra;
          unsigned foldv = ya ? s_fb : s_fa;
          unsigned birth = ya ? s_fa : s_fb;
          // snapshot on lane j (its state at time j)
          bool me = (lane == j);
          sdiff = me ? 1 : sdiff;
          syoung = me ? young : syoung;
          sold = me ? oldv : sold;
          sbirth = me ? birth : sbirth;
          // patch every lane's in-flight roots with substitution young->old
          bool ma = (ra == young);
          ra = ma ? oldv : ra;
          fa = ma ? foldv : fa;
          bool mb = (rb == young);
          rb = mb ? oldv : rb;
          fb = mb ? foldv : fb;
        }
      }
      // post-sweep: record pairs (multiset order) and apply parent updates
      unsigned long long mask = __ballot(sdiff);
      int rank = __popcll(mask & ((1ULL << lane) - 1ULL));
      if (sdiff) {
        pairs[cntbase + rank] = ((unsigned long long)sbirth << 32) | wbits;
        par[syoung] = sold;  // distinct youngs -> no write collisions
      }
      cntbase += (int)__popcll(mask);
    }
    if (lane == 0) cntS = cntbase;
  }
  __syncthreads();
  const int cnt = cntS;
  const int wid = tid >> 6, lane = tid & 63;
  // landscape: top-2 tents per t (zero-persistence pairs contribute 0, as in ref)
  for (int t = wid; t < TT; t += 4) {
    double tvd = (t == 24) ? 0.5 : (double)t * (0.5 / 24.0);
    float tv = (float)tvd;
    float m1 = 0.0f, m2 = 0.0f;
    for (int pidx = lane; pidx < cnt; pidx += 64) {
      unsigned long long pr = pairs[pidx];
      float pbv = __uint_as_float((unsigned)(pr >> 32));
      float pdv = __uint_as_float((unsigned)pr);
      float tent = fminf(tv - pbv, pdv - tv);
      tent = fmaxf(tent, 0.0f);
      if (tent > m1) { m2 = m1; m1 = tent; }
      else if (tent > m2) { m2 = tent; }
    }
    #pragma unroll
    for (int off = 32; off; off >>= 1) {
      float o1 = __shfl_xor(m1, off, 64);
      float o2 = __shfl_xor(m2, off, 64);
      float n1 = fmaxf(m1, o1);
      float n2 = fmaxf(fminf(m1, o1), fmaxf(m2, o2));
      m1 = n1; m2 = n2;
    }
    if (lane == 0) { feat[t] = m1; feat[TT + t] = m2; }
  }
  __syncthreads();
  // MLP: relu(feat @ w_topo + b_topo) @ w_fc + b_fc
  if (tid < 100) {
    double h = (double)b_topo[tid];
    for (int k2 = 0; k2 < 50; ++k2) h += (double)feat[k2] * (double)w_topo[k2 * 100 + tid];
    hbuf[tid] = (h > 0.0) ? (float)h : 0.0f;
  }
  __syncthreads();
  if (tid < 10) {
    double o = (double)b_fc[tid];
    for (int k2 = 0; k2 < 100; ++k2) o += (double)hbuf[k2] * (double)w_fc[k2 * 10 + tid];
    out[b * 10 + tid] = (float)o;
  }
}

extern "C" void kernel_launch(void* const* d_in, const int* in_sizes, int n_in,
                              void* d_out, int out_size, void* d_ws, size_t ws_size,
                              hipStream_t stream) {
  const float* x = (const float*)d_in[0];
  const float* w_topo = (const float*)d_in[1];
  const float* b_topo = (const float*)d_in[2];
  const float* w_fc = (const float*)d_in[3];
  const float* b_fc = (const float*)d_in[4];
  float* outp = (float*)d_out;
  char* ws = (char*)d_ws;
  int* ORDER = (int*)ws;
  float* D2S = (float*)(ws + 2458624);
  float* M = (float*)(ws + 4917248);
  float* F = (float*)(ws + 5318656);

  hipLaunchKernelGGL(k_sortrows, dim3(VV), dim3(256), 0, stream, ORDER, D2S);
  hipLaunchKernelGGL(k_norm, dim3(128), dim3(256), 0, stream, x, M);
  hipLaunchKernelGGL(k_dtm, dim3((128 * VV + 3) / 4), dim3(256), 0, stream, M, ORDER, D2S, F);
  hipLaunchKernelGGL(k_main, dim3(128), dim3(256), 0, stream, F, w_topo, b_topo, w_fc, b_fc, outp);
}